// Round 1
// baseline (346.761 us; speedup 1.0000x reference)
//
#include <hip/hip_runtime.h>
#include <stdint.h>

// KMeans top-2 distance gap: N=1M points x D=64, K=128 centroids, fp32.
// S = X * C^T via bf16 MFMA (16x16x32), fused epilogue computes
// d2 = csq[c] - 2*s (||x||^2 cancels in the top-2 difference) and the
// per-row top-2 min reduction. Memory-bound target ~41 us (260 MB @ 6.3 TB/s).

#define DD 64
#define KK 128

typedef __attribute__((ext_vector_type(8))) short bf16x8;   // 8 bf16 = 4 VGPRs
typedef __attribute__((ext_vector_type(4))) float f32x4;
typedef __attribute__((ext_vector_type(4))) unsigned int u32x4;

// round-to-nearest-even fp32 -> bf16, packed pair (low = a, high = b)
__device__ __forceinline__ uint32_t pk_bf16(float a, float b) {
  uint32_t ua = __builtin_bit_cast(uint32_t, a);
  uint32_t ub = __builtin_bit_cast(uint32_t, b);
  ua += 0x7fffu + ((ua >> 16) & 1u);
  ub += 0x7fffu + ((ub >> 16) & 1u);
  return (ua >> 16) | (ub & 0xffff0000u);
}

__global__ __launch_bounds__(256, 3) void kmeans_top2_kernel(
    const float* __restrict__ x, const float* __restrict__ cent,
    float* __restrict__ out, int N) {
  // B fragments for mfma_f32_16x16x32_bf16, fragment-ordered:
  // slot th = t*2+h (tile t: centroid cols 16t..16t+15, half h: k 32h..32h+31)
  // lane l supplies B[k=(l>>4)*8+j][col=(l&15)+16t] = cent[(l&15)+16t][(l>>4)*8+j+32h]
  __shared__ uint32_t fragB[16 * 64 * 4];  // 16 KB
  __shared__ float csq_lds[KK];

  const int tid = threadIdx.x;

  // ---- phase 1: convert centroids to bf16 fragments in LDS (once/block) ----
  #pragma unroll
  for (int i = 0; i < 4; ++i) {
    int s = tid + i * 256;           // 1024 slots
    int l = s & 63;
    int th = s >> 6;
    int t = th >> 1, h = th & 1;
    int c = (l & 15) + 16 * t;
    int kb = ((l >> 4) << 3) + 32 * h;
    const float4* p = (const float4*)(cent + c * DD + kb);
    float4 f0 = p[0];
    float4 f1 = p[1];
    uint32_t* dst = &fragB[s * 4];
    dst[0] = pk_bf16(f0.x, f0.y);
    dst[1] = pk_bf16(f0.z, f0.w);
    dst[2] = pk_bf16(f1.x, f1.y);
    dst[3] = pk_bf16(f1.z, f1.w);
  }
  // centroid squared norms (fp32, exact)
  if (tid < KK) {
    const float4* p = (const float4*)(cent + tid * DD);
    float s = 0.f;
    #pragma unroll
    for (int i = 0; i < 16; ++i) {
      float4 f = p[i];
      s = fmaf(f.x, f.x, s);
      s = fmaf(f.y, f.y, s);
      s = fmaf(f.z, f.z, s);
      s = fmaf(f.w, f.w, s);
    }
    csq_lds[tid] = s;
  }
  __syncthreads();

  const int lane = tid & 63;
  const int q = lane >> 4;   // quad 0..3
  const int li = lane & 15;
  const int gwave = blockIdx.x * 4 + (tid >> 6);
  const int nwaves = gridDim.x * 4;

  // ---- hold all B fragments + csq in registers across the whole loop ----
  bf16x8 bfr[16];
  #pragma unroll
  for (int th = 0; th < 16; ++th)
    bfr[th] = *(const bf16x8*)&fragB[(th * 64 + lane) * 4];

  float cs[8];
  #pragma unroll
  for (int t = 0; t < 8; ++t) cs[t] = csq_lds[t * 16 + li];

  const int ngroups = (N + 15) >> 4;

  // ---- main grid-stride loop: 16 points per wave per group ----
  for (int g = gwave; g < ngroups; g += nwaves) {
    int row = g * 16 + li;
    int rowc = row < N ? row : N - 1;
    // A fragment: lane supplies x[row=li][k=q*8+j] (+32 for half 1)
    const float4* p = (const float4*)(x + (size_t)rowc * DD + q * 8);
    float4 f0 = p[0], f1 = p[1];   // k = q*8 .. q*8+8
    float4 f2 = p[8], f3 = p[9];   // k = 32+q*8 .. +8
    u32x4 ua, ub;
    ua.x = pk_bf16(f0.x, f0.y);
    ua.y = pk_bf16(f0.z, f0.w);
    ua.z = pk_bf16(f1.x, f1.y);
    ua.w = pk_bf16(f1.z, f1.w);
    ub.x = pk_bf16(f2.x, f2.y);
    ub.y = pk_bf16(f2.z, f2.w);
    ub.z = pk_bf16(f3.x, f3.y);
    ub.w = pk_bf16(f3.z, f3.w);
    bf16x8 A0 = __builtin_bit_cast(bf16x8, ua);
    bf16x8 A1 = __builtin_bit_cast(bf16x8, ub);

    f32x4 acc[8];
    #pragma unroll
    for (int t = 0; t < 8; ++t) acc[t] = (f32x4){0.f, 0.f, 0.f, 0.f};
    #pragma unroll
    for (int t = 0; t < 8; ++t) {
      acc[t] = __builtin_amdgcn_mfma_f32_16x16x32_bf16(A0, bfr[2 * t], acc[t], 0, 0, 0);
      acc[t] = __builtin_amdgcn_mfma_f32_16x16x32_bf16(A1, bfr[2 * t + 1], acc[t], 0, 0, 0);
    }

    // epilogue: lane holds D[row=q*4+r][col=li+16t]; top-2 min per row
    float res1[4], res2[4];
    #pragma unroll
    for (int r = 0; r < 4; ++r) {
      float m1 = 3.4e38f, m2 = 3.4e38f;
      #pragma unroll
      for (int t = 0; t < 8; ++t) {
        float d = fmaf(-2.f, acc[t][r], cs[t]);
        float lo = fminf(m1, d);
        m2 = fminf(m2, fmaxf(m1, d));
        m1 = lo;
      }
      // butterfly merge across the 16 lanes of this quad (xor<16 stays in quad)
      #pragma unroll
      for (int m = 1; m < 16; m <<= 1) {
        float o1 = __shfl_xor(m1, m, 64);
        float o2 = __shfl_xor(m2, m, 64);
        float lo = fminf(m1, o1);
        m2 = fminf(fminf(m2, o2), fmaxf(m1, o1));
        m1 = lo;
      }
      res1[r] = m1;
      res2[r] = m2;
    }

    // lanes li<4 of each quad write rows base+q*4+li -> 64B contiguous/wave
    if (li < 4) {
      int prow = g * 16 + q * 4 + li;
      if (prow < N) {
        float v1 = li == 0 ? res1[0] : li == 1 ? res1[1] : li == 2 ? res1[2] : res1[3];
        float v2 = li == 0 ? res2[0] : li == 1 ? res2[1] : li == 2 ? res2[2] : res2[3];
        out[prow] = v2 - v1;
      }
    }
  }
}

extern "C" void kernel_launch(void* const* d_in, const int* in_sizes, int n_in,
                              void* d_out, int out_size, void* d_ws, size_t ws_size,
                              hipStream_t stream) {
  const float* x = (const float*)d_in[0];
  const float* cent = (const float*)d_in[1];
  float* out = (float*)d_out;
  int N = in_sizes[0] / DD;
  int ngroups = (N + 15) / 16;
  int nblocks = (ngroups + 3) / 4;
  if (nblocks > 2048) nblocks = 2048;
  kmeans_top2_kernel<<<dim3(nblocks), dim3(256), 0, stream>>>(x, cent, out, N);
}